// Round 1
// baseline (356.683 us; speedup 1.0000x reference)
//
#include <hip/hip_runtime.h>
#include <stdint.h>

#define HH 512
#define WW 512
#define WPR 8                 // u64 words per row (512 bits)
#define NWORDS (HH * WPR)     // 4096 words per image
#define NTHREADS 1024
#define WPT (NWORDS / NTHREADS) // 4 words per thread

typedef unsigned long long u64;

__device__ __forceinline__ u64 ldw(const u64* M, int r, int c) {
    return (r < 0 || r >= HH || c < 0 || c >= WPR) ? 0ULL : M[r * WPR + c];
}

// One Zhang-Suen sub-step for word (r,c): returns the new word.
// Bit k of a word = pixel col c*64+k. East neighbor (col+1) = (w>>1)|(next<<63).
__device__ __forceinline__ u64 zs_word(const u64* M, int r, int c, int step) {
    u64 nm = ldw(M, r - 1, c - 1), nc = ldw(M, r - 1, c), np = ldw(M, r - 1, c + 1);
    u64 cm = ldw(M, r,     c - 1), cc = ldw(M, r,     c), cp = ldw(M, r,     c + 1);
    u64 sm = ldw(M, r + 1, c - 1), sc = ldw(M, r + 1, c), sp = ldw(M, r + 1, c + 1);

    u64 P2 = nc;                         // N
    u64 P3 = (nc >> 1) | (np << 63);     // NE
    u64 P4 = (cc >> 1) | (cp << 63);     // E
    u64 P5 = (sc >> 1) | (sp << 63);     // SE
    u64 P6 = sc;                         // S
    u64 P7 = (sc << 1) | (sm >> 63);     // SW
    u64 P8 = (cc << 1) | (cm >> 63);     // W
    u64 P9 = (nc << 1) | (nm >> 63);     // NW

    // B = popcount of 8 neighbors, bit-sliced adder tree -> b3 b2 b1 b0
    u64 ab = P2 ^ P3;
    u64 s1 = ab ^ P4, c1 = (P2 & P3) | (ab & P4);
    u64 de = P5 ^ P6;
    u64 s2 = de ^ P7, c2 = (P5 & P6) | (de & P7);
    u64 s3 = P8 ^ P9, c3 = P8 & P9;
    u64 gh = s1 ^ s2;
    u64 b0 = gh ^ s3, c4 = (s1 & s2) | (gh & s3);
    u64 ij = c1 ^ c2;
    u64 s4 = ij ^ c3, c5 = (c1 & c2) | (ij & c3);
    u64 b1 = s4 ^ c4, c6 = s4 & c4;
    u64 b2 = c5 ^ c6, b3 = c5 & c6;

    u64 Bge2 = b1 | b2 | b3;                 // B >= 2
    u64 Ble6 = ~(b3 | (b2 & b1 & b0));       // B <= 6 (exclude 7 and 8)

    // A == 1: exactly one 0->1 transition around P2..P9..P2
    u64 a1, a2, t;
    t = ~P2 & P3; a1 = t; a2 = 0ULL;
    t = ~P3 & P4; a2 |= a1 & t; a1 |= t;
    t = ~P4 & P5; a2 |= a1 & t; a1 |= t;
    t = ~P5 & P6; a2 |= a1 & t; a1 |= t;
    t = ~P6 & P7; a2 |= a1 & t; a1 |= t;
    t = ~P7 & P8; a2 |= a1 & t; a1 |= t;
    t = ~P8 & P9; a2 |= a1 & t; a1 |= t;
    t = ~P9 & P2; a2 |= a1 & t; a1 |= t;
    u64 Aeq1 = a1 & ~a2;

    u64 sccond;
    if (step == 0) sccond = ~(P2 & P4 & P6) & ~(P4 & P6 & P8);
    else           sccond = ~(P2 & P4 & P8) & ~(P2 & P6 & P8);

    u64 rem = Bge2 & Ble6 & Aeq1 & sccond;
    return cc & ~rem;
}

// Dilation by integer disk of radius 3 (dy^2+dx^2 <= 9) of word (r,c).
__device__ __forceinline__ u64 dil3_word(const u64* M, int r, int c) {
    u64 cm = ldw(M, r, c - 1), cc = ldw(M, r, c), cp = ldw(M, r, c + 1);
    // row 0: |dx| <= 3
    u64 h = cc
          | (cc >> 1) | (cp << 63)
          | (cc >> 2) | (cp << 62)
          | (cc >> 3) | (cp << 61)
          | (cc << 1) | (cm >> 63)
          | (cc << 2) | (cm >> 62)
          | (cc << 3) | (cm >> 61);
    // rows +-1, +-2: |dx| <= 2
    u64 um = ldw(M, r - 1, c - 1) | ldw(M, r + 1, c - 1) | ldw(M, r - 2, c - 1) | ldw(M, r + 2, c - 1);
    u64 uc = ldw(M, r - 1, c    ) | ldw(M, r + 1, c    ) | ldw(M, r - 2, c    ) | ldw(M, r + 2, c    );
    u64 up = ldw(M, r - 1, c + 1) | ldw(M, r + 1, c + 1) | ldw(M, r - 2, c + 1) | ldw(M, r + 2, c + 1);
    h |= uc
       | (uc >> 1) | (up << 63)
       | (uc >> 2) | (up << 62)
       | (uc << 1) | (um >> 63)
       | (uc << 2) | (um >> 62);
    // rows +-3: dx == 0
    h |= ldw(M, r - 3, c) | ldw(M, r + 3, c);
    return h;
}

__device__ __forceinline__ void pack_mask(u64* M, const float* __restrict__ src) {
    // 16 waves; wave w packs words [w*256, (w+1)*256). One ballot per 64 pixels.
    int lane = threadIdx.x & 63;
    int wave = threadIdx.x >> 6;
    int beg = wave * (NWORDS / 16);
    int end = beg + (NWORDS / 16);
    for (int wi = beg; wi < end; ++wi) {
        float v = src[wi * 64 + lane];
        u64 word = __ballot(v > 0.5f);
        if (lane == 0) M[wi] = word;
    }
}

__device__ void skeletonize(u64* M, volatile int* s_changed) {
    int tid = threadIdx.x;
    if (tid == 0) *s_changed = 0;
    for (;;) {
        bool ch = false;
        for (int step = 0; step < 2; ++step) {
            __syncthreads();   // prior writes (and flag reset) visible
            u64 nw[WPT];
            #pragma unroll
            for (int k = 0; k < WPT; ++k) {
                int wi = k * NTHREADS + tid;     // lane-consecutive words
                nw[k] = zs_word(M, wi >> 3, wi & 7, step);
            }
            __syncthreads();   // all reads done before writes
            #pragma unroll
            for (int k = 0; k < WPT; ++k) {
                int wi = k * NTHREADS + tid;
                if (nw[k] != M[wi]) { M[wi] = nw[k]; ch = true; }
            }
        }
        if (ch) *s_changed = 1;
        __syncthreads();
        int stop = (*s_changed == 0);
        __syncthreads();       // everyone has read the flag
        if (stop) break;
        if (tid == 0) *s_changed = 0;
    }
}

__global__ __launch_bounds__(NTHREADS)
void ccq_kernel(const float* __restrict__ y_pred,
                const float* __restrict__ y_true,
                float* __restrict__ metrics /* [16][3] in ws */) {
    __shared__ u64 M[NWORDS];        // 32 KB working image
    __shared__ int s_changed;
    __shared__ int s_acc[4];         // cp, cg, tp, fnhit

    int b = blockIdx.x;
    int tid = threadIdx.x;
    const float* pred = y_pred + (size_t)b * HH * WW;
    const float* gt   = y_true + (size_t)b * HH * WW;

    // ---- skeletonize p ----
    pack_mask(M, pred);
    skeletonize(M, &s_changed);

    // stash skel_p and its radius-3 dilation in registers
    u64 pA[WPT], dA[WPT];
    #pragma unroll
    for (int k = 0; k < WPT; ++k) {
        int wi = k * NTHREADS + tid;
        pA[k] = M[wi];
        dA[k] = dil3_word(M, wi >> 3, wi & 7);
    }
    __syncthreads();   // done reading p before overwrite

    // ---- skeletonize g (same buffer) ----
    pack_mask(M, gt);
    skeletonize(M, &s_changed);

    if (tid < 4) s_acc[tid] = 0;
    __syncthreads();

    int cp = 0, cg = 0, tp = 0, fnh = 0;
    #pragma unroll
    for (int k = 0; k < WPT; ++k) {
        int wi = k * NTHREADS + tid;
        u64 gw = M[wi];
        cp  += __popcll(pA[k]);
        cg  += __popcll(gw);
        tp  += __popcll(pA[k] & dil3_word(M, wi >> 3, wi & 7)); // p within dist<=3 of g
        fnh += __popcll(gw & dA[k]);                            // g within dist<=3 of p
    }
    // wave reduce then LDS atomics
    #pragma unroll
    for (int o = 32; o > 0; o >>= 1) {
        cp  += __shfl_down(cp, o);
        cg  += __shfl_down(cg, o);
        tp  += __shfl_down(tp, o);
        fnh += __shfl_down(fnh, o);
    }
    if ((tid & 63) == 0) {
        atomicAdd(&s_acc[0], cp);
        atomicAdd(&s_acc[1], cg);
        atomicAdd(&s_acc[2], tp);
        atomicAdd(&s_acc[3], fnh);
    }
    __syncthreads();

    if (tid == 0) {
        float TP = (float)s_acc[2];
        float FP = (float)(s_acc[0] - s_acc[2]);
        float FN = (float)(s_acc[1] - s_acc[3]);
        float corr  = TP / (TP + FP + 1e-12f);
        float compl_ = TP / (TP + FN + 1e-12f);
        float qual  = TP / (TP + FP + FN + 1e-12f);
        metrics[b * 3 + 0] = corr;
        metrics[b * 3 + 1] = compl_;
        metrics[b * 3 + 2] = qual;
    }
}

__global__ void ccq_reduce(const float* __restrict__ metrics, float* __restrict__ out) {
    int k = threadIdx.x;
    if (k < 3) {
        float s = 0.0f;
        for (int b = 0; b < 16; ++b) s += metrics[b * 3 + k];
        out[k] = s * (1.0f / 16.0f);
    }
}

extern "C" void kernel_launch(void* const* d_in, const int* in_sizes, int n_in,
                              void* d_out, int out_size, void* d_ws, size_t ws_size,
                              hipStream_t stream) {
    (void)in_sizes; (void)n_in; (void)out_size; (void)ws_size;
    const float* y_pred = (const float*)d_in[0];
    const float* y_true = (const float*)d_in[1];
    float* out = (float*)d_out;
    float* metrics = (float*)d_ws;   // 48 floats of scratch

    hipLaunchKernelGGL(ccq_kernel, dim3(16), dim3(NTHREADS), 0, stream,
                       y_pred, y_true, metrics);
    hipLaunchKernelGGL(ccq_reduce, dim3(1), dim3(64), 0, stream, metrics, out);
}

// Round 2
// 245.820 us; speedup vs baseline: 1.4510x; 1.4510x over previous
//
#include <hip/hip_runtime.h>
#include <stdint.h>

#define HH 512
#define WW 512
#define WPR 8                 // u64 words per row (512 bits)
#define NWORDS (HH * WPR)     // 4096 words per image
#define NTHREADS 1024
#define WPT (NWORDS / NTHREADS) // 4 words per thread
#define NB 16                 // batch

typedef unsigned long long u64;

__device__ __forceinline__ u64 ldw(const u64* M, int r, int c) {
    return (r < 0 || r >= HH || c < 0 || c >= WPR) ? 0ULL : M[r * WPR + c];
}

// One Zhang-Suen sub-step for word (r,c): returns the new word.
// Bit k of a word = pixel col c*64+k. East neighbor (col+1) = (w>>1)|(next<<63).
__device__ __forceinline__ u64 zs_word(const u64* M, int r, int c, int step) {
    u64 nm = ldw(M, r - 1, c - 1), nc = ldw(M, r - 1, c), np = ldw(M, r - 1, c + 1);
    u64 cm = ldw(M, r,     c - 1), cc = ldw(M, r,     c), cp = ldw(M, r,     c + 1);
    u64 sm = ldw(M, r + 1, c - 1), sc = ldw(M, r + 1, c), sp = ldw(M, r + 1, c + 1);

    u64 P2 = nc;                         // N
    u64 P3 = (nc >> 1) | (np << 63);     // NE
    u64 P4 = (cc >> 1) | (cp << 63);     // E
    u64 P5 = (sc >> 1) | (sp << 63);     // SE
    u64 P6 = sc;                         // S
    u64 P7 = (sc << 1) | (sm >> 63);     // SW
    u64 P8 = (cc << 1) | (cm >> 63);     // W
    u64 P9 = (nc << 1) | (nm >> 63);     // NW

    // B = popcount of 8 neighbors, bit-sliced adder tree -> b3 b2 b1 b0
    u64 ab = P2 ^ P3;
    u64 s1 = ab ^ P4, c1 = (P2 & P3) | (ab & P4);
    u64 de = P5 ^ P6;
    u64 s2 = de ^ P7, c2 = (P5 & P6) | (de & P7);
    u64 s3 = P8 ^ P9, c3 = P8 & P9;
    u64 gh = s1 ^ s2;
    u64 b0 = gh ^ s3, c4 = (s1 & s2) | (gh & s3);
    u64 ij = c1 ^ c2;
    u64 s4 = ij ^ c3, c5 = (c1 & c2) | (ij & c3);
    u64 b1 = s4 ^ c4, c6 = s4 & c4;
    u64 b2 = c5 ^ c6, b3 = c5 & c6;

    u64 Bge2 = b1 | b2 | b3;                 // B >= 2
    u64 Ble6 = ~(b3 | (b2 & b1 & b0));       // B <= 6

    // A == 1: exactly one 0->1 transition around P2..P9..P2
    u64 a1, a2, t;
    t = ~P2 & P3; a1 = t; a2 = 0ULL;
    t = ~P3 & P4; a2 |= a1 & t; a1 |= t;
    t = ~P4 & P5; a2 |= a1 & t; a1 |= t;
    t = ~P5 & P6; a2 |= a1 & t; a1 |= t;
    t = ~P6 & P7; a2 |= a1 & t; a1 |= t;
    t = ~P7 & P8; a2 |= a1 & t; a1 |= t;
    t = ~P8 & P9; a2 |= a1 & t; a1 |= t;
    t = ~P9 & P2; a2 |= a1 & t; a1 |= t;
    u64 Aeq1 = a1 & ~a2;

    u64 sccond;
    if (step == 0) sccond = ~(P2 & P4 & P6) & ~(P4 & P6 & P8);
    else           sccond = ~(P2 & P4 & P8) & ~(P2 & P6 & P8);

    u64 rem = Bge2 & Ble6 & Aeq1 & sccond;
    return cc & ~rem;
}

// Dilation by integer disk of radius 3 (dy^2+dx^2 <= 9) of word (r,c).
__device__ __forceinline__ u64 dil3_word(const u64* M, int r, int c) {
    u64 cm = ldw(M, r, c - 1), cc = ldw(M, r, c), cp = ldw(M, r, c + 1);
    u64 h = cc
          | (cc >> 1) | (cp << 63)
          | (cc >> 2) | (cp << 62)
          | (cc >> 3) | (cp << 61)
          | (cc << 1) | (cm >> 63)
          | (cc << 2) | (cm >> 62)
          | (cc << 3) | (cm >> 61);
    u64 um = ldw(M, r - 1, c - 1) | ldw(M, r + 1, c - 1) | ldw(M, r - 2, c - 1) | ldw(M, r + 2, c - 1);
    u64 uc = ldw(M, r - 1, c    ) | ldw(M, r + 1, c    ) | ldw(M, r - 2, c    ) | ldw(M, r + 2, c    );
    u64 up = ldw(M, r - 1, c + 1) | ldw(M, r + 1, c + 1) | ldw(M, r - 2, c + 1) | ldw(M, r + 2, c + 1);
    h |= uc
       | (uc >> 1) | (up << 63)
       | (uc >> 2) | (up << 62)
       | (uc << 1) | (um >> 63)
       | (uc << 2) | (um >> 62);
    h |= ldw(M, r - 3, c) | ldw(M, r + 3, c);
    return h;
}

__device__ __forceinline__ void pack_mask(u64* M, const float* __restrict__ src) {
    int lane = threadIdx.x & 63;
    int wave = threadIdx.x >> 6;
    int beg = wave * (NWORDS / 16);
    int end = beg + (NWORDS / 16);
    for (int wi = beg; wi < end; ++wi) {
        float v = src[wi * 64 + lane];
        u64 word = __ballot(v > 0.5f);
        if (lane == 0) M[wi] = word;
    }
}

// Dirty-byte array padded: (HH+2) rows x (WPR+2) cols of bytes.
// D[(r+1)*(WPR+2) + (c+1)] bit0 = changed last sub-step, bit1 = changed two ago.
#define DPITCH (WPR + 2)
#define DSZ ((HH + 2) * DPITCH)

__global__ __launch_bounds__(NTHREADS)
void skel_kernel(const float* __restrict__ y_pred,
                 const float* __restrict__ y_true,
                 u64* __restrict__ skel /* [32][NWORDS] */) {
    __shared__ u64 M[NWORDS];           // 32 KB working image
    __shared__ unsigned char D[DSZ];    // ~5.1 KB dirty history
    __shared__ int s_any[2];

    int bx = blockIdx.x;
    int tid = threadIdx.x;
    const float* src = (bx < NB) ? y_pred + (size_t)bx * HH * WW
                                 : y_true + (size_t)(bx - NB) * HH * WW;

    pack_mask(M, src);

    // init dirty: interior = 3 (force full compute of first two sub-steps), pad = 0
    for (int i = tid; i < DSZ; i += NTHREADS) {
        int r = i / DPITCH, c = i - r * DPITCH;
        D[i] = (r >= 1 && r <= HH && c >= 1 && c <= WPR) ? 3 : 0;
    }
    if (tid < 2) s_any[tid] = 0;

    int p = 0;
    for (;;) {
        for (int step = 0; step < 2; ++step) {
            __syncthreads();   // prior writes (M, D, flags) visible
            u64 nw[WPT];
            unsigned char nd[WPT];
            bool any = false;
            #pragma unroll
            for (int k = 0; k < WPT; ++k) {
                int wi = k * NTHREADS + tid;
                int r = wi >> 3, c = wi & 7;
                int di = (r + 1) * DPITCH + (c + 1);
                unsigned need = D[di - DPITCH - 1] | D[di - DPITCH] | D[di - DPITCH + 1]
                              | D[di - 1]          | D[di]          | D[di + 1]
                              | D[di + DPITCH - 1] | D[di + DPITCH] | D[di + DPITCH + 1];
                u64 cur = M[wi];
                u64 nv = cur;
                if (need) nv = zs_word(M, r, c, step);
                bool chg = (nv != cur);
                nw[k] = nv;
                nd[k] = (unsigned char)(((D[di] << 1) & 2) | (chg ? 1 : 0));
                any |= chg;
            }
            __syncthreads();   // all reads done before writes
            #pragma unroll
            for (int k = 0; k < WPT; ++k) {
                int wi = k * NTHREADS + tid;
                int r = wi >> 3, c = wi & 7;
                M[wi] = nw[k];
                D[(r + 1) * DPITCH + (c + 1)] = nd[k];
            }
            if (any) s_any[p] = 1;
        }
        __syncthreads();       // iteration's writes + flag visible
        int done = (s_any[p] == 0);
        if (tid == 0) s_any[p ^ 1] = 0;  // pre-clear other slot for next iter
        p ^= 1;
        if (done) break;       // uniform across block
    }

    // store packed skeleton (lane-consecutive u64 -> coalesced 512B/wave)
    u64* dst = skel + (size_t)bx * NWORDS;
    #pragma unroll
    for (int k = 0; k < WPT; ++k) {
        int wi = k * NTHREADS + tid;
        dst[wi] = M[wi];
    }
}

__global__ __launch_bounds__(NTHREADS)
void count_kernel(const u64* __restrict__ skel,
                  float* __restrict__ metrics /* [16][3] */) {
    __shared__ u64 P[NWORDS];
    __shared__ u64 G[NWORDS];
    __shared__ int s_acc[4];

    int b = blockIdx.x;
    int tid = threadIdx.x;
    const u64* sp = skel + (size_t)b * NWORDS;
    const u64* sg = skel + (size_t)(NB + b) * NWORDS;
    for (int i = tid; i < NWORDS; i += NTHREADS) { P[i] = sp[i]; G[i] = sg[i]; }
    if (tid < 4) s_acc[tid] = 0;
    __syncthreads();

    int cp = 0, cg = 0, tp = 0, fnh = 0;
    #pragma unroll
    for (int k = 0; k < WPT; ++k) {
        int wi = k * NTHREADS + tid;
        int r = wi >> 3, c = wi & 7;
        u64 pw = P[wi], gw = G[wi];
        cp  += __popcll(pw);
        cg  += __popcll(gw);
        tp  += __popcll(pw & dil3_word(G, r, c));  // p within dist<=3 of g
        fnh += __popcll(gw & dil3_word(P, r, c));  // g within dist<=3 of p
    }
    #pragma unroll
    for (int o = 32; o > 0; o >>= 1) {
        cp  += __shfl_down(cp, o);
        cg  += __shfl_down(cg, o);
        tp  += __shfl_down(tp, o);
        fnh += __shfl_down(fnh, o);
    }
    if ((tid & 63) == 0) {
        atomicAdd(&s_acc[0], cp);
        atomicAdd(&s_acc[1], cg);
        atomicAdd(&s_acc[2], tp);
        atomicAdd(&s_acc[3], fnh);
    }
    __syncthreads();

    if (tid == 0) {
        float TP = (float)s_acc[2];
        float FP = (float)(s_acc[0] - s_acc[2]);
        float FN = (float)(s_acc[1] - s_acc[3]);
        metrics[b * 3 + 0] = TP / (TP + FP + 1e-12f);
        metrics[b * 3 + 1] = TP / (TP + FN + 1e-12f);
        metrics[b * 3 + 2] = TP / (TP + FP + FN + 1e-12f);
    }
}

__global__ void ccq_reduce(const float* __restrict__ metrics, float* __restrict__ out) {
    int k = threadIdx.x;
    if (k < 3) {
        float s = 0.0f;
        for (int b = 0; b < NB; ++b) s += metrics[b * 3 + k];
        out[k] = s * (1.0f / NB);
    }
}

extern "C" void kernel_launch(void* const* d_in, const int* in_sizes, int n_in,
                              void* d_out, int out_size, void* d_ws, size_t ws_size,
                              hipStream_t stream) {
    (void)in_sizes; (void)n_in; (void)out_size; (void)ws_size;
    const float* y_pred = (const float*)d_in[0];
    const float* y_true = (const float*)d_in[1];
    float* out = (float*)d_out;

    u64* skel = (u64*)d_ws;                               // 32 * 4096 * 8 = 1 MB
    float* metrics = (float*)((char*)d_ws + (size_t)2 * NB * NWORDS * sizeof(u64));

    hipLaunchKernelGGL(skel_kernel, dim3(2 * NB), dim3(NTHREADS), 0, stream,
                       y_pred, y_true, skel);
    hipLaunchKernelGGL(count_kernel, dim3(NB), dim3(NTHREADS), 0, stream,
                       skel, metrics);
    hipLaunchKernelGGL(ccq_reduce, dim3(1), dim3(64), 0, stream, metrics, out);
}

// Round 3
// 131.323 us; speedup vs baseline: 2.7161x; 1.8719x over previous
//
#include <hip/hip_runtime.h>
#include <stdint.h>

#define HH 512
#define WW 512
#define WPR 8                 // u64 words per row (512 bits)
#define NWORDS (HH * WPR)     // 4096 words per image
#define NTHREADS 1024
#define WPT (NWORDS / NTHREADS) // 4
#define NB 16                 // batch

typedef unsigned long long u64;

__device__ __forceinline__ u64 ldw(const u64* M, int r, int c) {
    return (r < 0 || r >= HH || c < 0 || c >= WPR) ? 0ULL : M[r * WPR + c];
}

// One Zhang-Suen sub-step for word (r,c). Bit k = pixel col c*64+k.
__device__ __forceinline__ u64 zs_word(const u64* M, int r, int c, int step) {
    u64 nm = ldw(M, r - 1, c - 1), nc = ldw(M, r - 1, c), np = ldw(M, r - 1, c + 1);
    u64 cm = ldw(M, r,     c - 1), cc = ldw(M, r,     c), cp = ldw(M, r,     c + 1);
    u64 sm = ldw(M, r + 1, c - 1), sc = ldw(M, r + 1, c), sp = ldw(M, r + 1, c + 1);

    u64 P2 = nc;
    u64 P3 = (nc >> 1) | (np << 63);
    u64 P4 = (cc >> 1) | (cp << 63);
    u64 P5 = (sc >> 1) | (sp << 63);
    u64 P6 = sc;
    u64 P7 = (sc << 1) | (sm >> 63);
    u64 P8 = (cc << 1) | (cm >> 63);
    u64 P9 = (nc << 1) | (nm >> 63);

    u64 ab = P2 ^ P3;
    u64 s1 = ab ^ P4, c1 = (P2 & P3) | (ab & P4);
    u64 de = P5 ^ P6;
    u64 s2 = de ^ P7, c2 = (P5 & P6) | (de & P7);
    u64 s3 = P8 ^ P9, c3 = P8 & P9;
    u64 gh = s1 ^ s2;
    u64 b0 = gh ^ s3, c4 = (s1 & s2) | (gh & s3);
    u64 ij = c1 ^ c2;
    u64 s4 = ij ^ c3, c5 = (c1 & c2) | (ij & c3);
    u64 b1 = s4 ^ c4, c6 = s4 & c4;
    u64 b2 = c5 ^ c6, b3 = c5 & c6;

    u64 Bge2 = b1 | b2 | b3;
    u64 Ble6 = ~(b3 | (b2 & b1 & b0));

    u64 a1, a2, t;
    t = ~P2 & P3; a1 = t; a2 = 0ULL;
    t = ~P3 & P4; a2 |= a1 & t; a1 |= t;
    t = ~P4 & P5; a2 |= a1 & t; a1 |= t;
    t = ~P5 & P6; a2 |= a1 & t; a1 |= t;
    t = ~P6 & P7; a2 |= a1 & t; a1 |= t;
    t = ~P7 & P8; a2 |= a1 & t; a1 |= t;
    t = ~P8 & P9; a2 |= a1 & t; a1 |= t;
    t = ~P9 & P2; a2 |= a1 & t; a1 |= t;
    u64 Aeq1 = a1 & ~a2;

    u64 sccond;
    if (step == 0) sccond = ~(P2 & P4 & P6) & ~(P4 & P6 & P8);
    else           sccond = ~(P2 & P4 & P8) & ~(P2 & P6 & P8);

    return cc & ~(Bge2 & Ble6 & Aeq1 & sccond);
}

// ---------------- skeletonize: one block per mask (32 blocks) ----------------
// Dirty tracking: Cp[r+1] bit (c+1) set iff word (r,c) changed in either of the
// last two sub-steps. need(word r,c) = bits c..c+2 of Cp[r]|Cp[r+1]|Cp[r+2].
__global__ __launch_bounds__(NTHREADS)
void skel_kernel(const float* __restrict__ y_pred,
                 const float* __restrict__ y_true,
                 u64* __restrict__ skel /* [32][NWORDS] */,
                 int* __restrict__ cnt /* [16][4] */) {
    __shared__ u64 M[NWORDS];               // 32 KB
    __shared__ unsigned int Cp[HH + 2];     // padded row change masks
    __shared__ int s_any[2];

    int bx = blockIdx.x;
    int tid = threadIdx.x;
    int lane = tid & 63;

    if (bx == 0 && tid < 4 * NB) cnt[tid] = 0;   // zero counters for count pass

    const float* src = (bx < NB) ? y_pred + (size_t)bx * HH * WW
                                 : y_true + (size_t)(bx - NB) * HH * WW;

    // ---- pack: 16 pixels/thread/iter, float4 x4 loads + one ushort LDS store
    {
        unsigned short* M16 = (unsigned short*)M;
        const float4* s4 = (const float4*)src;
        #pragma unroll
        for (int i = 0; i < 16; ++i) {
            int t = i * NTHREADS + tid;          // ushort index, 0..16383
            float4 a = s4[t * 4 + 0];
            float4 b = s4[t * 4 + 1];
            float4 c = s4[t * 4 + 2];
            float4 d = s4[t * 4 + 3];
            unsigned bits =
                ((unsigned)(a.x > 0.5f) << 0)  | ((unsigned)(a.y > 0.5f) << 1)  |
                ((unsigned)(a.z > 0.5f) << 2)  | ((unsigned)(a.w > 0.5f) << 3)  |
                ((unsigned)(b.x > 0.5f) << 4)  | ((unsigned)(b.y > 0.5f) << 5)  |
                ((unsigned)(b.z > 0.5f) << 6)  | ((unsigned)(b.w > 0.5f) << 7)  |
                ((unsigned)(c.x > 0.5f) << 8)  | ((unsigned)(c.y > 0.5f) << 9)  |
                ((unsigned)(c.z > 0.5f) << 10) | ((unsigned)(c.w > 0.5f) << 11) |
                ((unsigned)(d.x > 0.5f) << 12) | ((unsigned)(d.y > 0.5f) << 13) |
                ((unsigned)(d.z > 0.5f) << 14) | ((unsigned)(d.w > 0.5f) << 15);
            M16[t] = (unsigned short)bits;
        }
    }

    // init row masks: interior rows fully dirty (forces first two sub-steps)
    for (int i = tid; i < HH + 2; i += NTHREADS)
        Cp[i] = (i >= 1 && i <= HH) ? 0x1FEu : 0u;
    if (tid < 2) s_any[tid] = 0;

    unsigned dl[WPT];                       // row-owner's "last sub-step" mask
    #pragma unroll
    for (int k = 0; k < WPT; ++k) dl[k] = 0x1FEu;

    int p = 0;
    for (;;) {
        for (int step = 0; step < 2; ++step) {
            __syncthreads();                // pack/init or prior writes visible
            u64 nv[WPT];
            u64 bal[WPT];
            bool anyc = false;
            #pragma unroll
            for (int k = 0; k < WPT; ++k) {
                int wi = k * NTHREADS + tid;
                int r = wi >> 3, c = wi & 7;
                unsigned need = ((Cp[r] | Cp[r + 1] | Cp[r + 2]) >> c) & 7u;
                bool chg = false;
                u64 x = 0;
                if (need) {
                    u64 cur = M[wi];
                    x = zs_word(M, r, c, step);
                    chg = (x != cur);
                }
                nv[k] = x;
                bal[k] = __ballot(chg);     // wave's 64 bits = 8 rows x 8 cols
                anyc |= (bal[k] != 0);
            }
            __syncthreads();                // all reads done before writes
            #pragma unroll
            for (int k = 0; k < WPT; ++k) {
                int wi = k * NTHREADS + tid;
                if ((bal[k] >> lane) & 1) M[wi] = nv[k];
                if ((lane & 7) == 0) {      // one owner lane per row
                    unsigned byte = ((unsigned)(bal[k] >> lane) & 0xFFu) << 1;
                    int idx = (wi >> 3) + 1;
                    Cp[idx] = byte | dl[k]; // union of last two sub-steps
                    dl[k] = byte;
                }
            }
            if (anyc) s_any[p] = 1;
        }
        __syncthreads();
        int done = (s_any[p] == 0);
        if (tid == 0) s_any[p ^ 1] = 0;
        p ^= 1;
        if (done) break;                    // uniform across block
    }

    u64* dst = skel + (size_t)bx * NWORDS;
    #pragma unroll
    for (int k = 0; k < WPT; ++k) {
        int wi = k * NTHREADS + tid;
        dst[wi] = M[wi];
    }
}

// ---------------- count: 8 strips/image, 128 blocks ----------------
#define STRIPS 8
#define SROWS (HH / STRIPS)   // 64 interior rows per strip
#define SR2 (SROWS + 6)       // + 3-row halo each side

__device__ __forceinline__ u64 ldws(const u64* M, int r, int c) {
    return (c < 0 || c >= WPR) ? 0ULL : M[r * WPR + c];   // rows always in range
}

// radius-3 disk dilation; strip-local r in [3, 3+SROWS)
__device__ __forceinline__ u64 dil3s(const u64* M, int r, int c) {
    u64 cm = ldws(M, r, c - 1), cc = ldws(M, r, c), cp = ldws(M, r, c + 1);
    u64 h = cc
          | (cc >> 1) | (cp << 63)
          | (cc >> 2) | (cp << 62)
          | (cc >> 3) | (cp << 61)
          | (cc << 1) | (cm >> 63)
          | (cc << 2) | (cm >> 62)
          | (cc << 3) | (cm >> 61);
    u64 um = ldws(M, r - 1, c - 1) | ldws(M, r + 1, c - 1) | ldws(M, r - 2, c - 1) | ldws(M, r + 2, c - 1);
    u64 uc = ldws(M, r - 1, c    ) | ldws(M, r + 1, c    ) | ldws(M, r - 2, c    ) | ldws(M, r + 2, c    );
    u64 up = ldws(M, r - 1, c + 1) | ldws(M, r + 1, c + 1) | ldws(M, r - 2, c + 1) | ldws(M, r + 2, c + 1);
    h |= uc
       | (uc >> 1) | (up << 63)
       | (uc >> 2) | (up << 62)
       | (uc << 1) | (um >> 63)
       | (uc << 2) | (um >> 62);
    h |= ldws(M, r - 3, c) | ldws(M, r + 3, c);
    return h;
}

__global__ __launch_bounds__(256)
void count_kernel(const u64* __restrict__ skel, int* __restrict__ cnt) {
    __shared__ u64 P[SR2 * WPR];
    __shared__ u64 G[SR2 * WPR];
    __shared__ int acc[4];

    int b = blockIdx.x / STRIPS;
    int s = blockIdx.x % STRIPS;
    int tid = threadIdx.x;
    int r0 = s * SROWS - 3;                 // global row of strip-local row 0

    const u64* sp = skel + (size_t)b * NWORDS;
    const u64* sg = skel + (size_t)(NB + b) * NWORDS;
    for (int i = tid; i < SR2 * WPR; i += 256) {
        int gr = r0 + (i >> 3);
        bool in = (gr >= 0 && gr < HH);
        int gi = gr * WPR + (i & 7);
        P[i] = in ? sp[gi] : 0ULL;
        G[i] = in ? sg[gi] : 0ULL;
    }
    if (tid < 4) acc[tid] = 0;
    __syncthreads();

    int cp = 0, cg = 0, tp = 0, fnh = 0;
    #pragma unroll
    for (int k = 0; k < 2; ++k) {
        int w = k * 256 + tid;              // 0..511 interior words
        int r = (w >> 3) + 3, c = w & 7;
        u64 pw = P[r * WPR + c], gw = G[r * WPR + c];
        cp  += __popcll(pw);
        cg  += __popcll(gw);
        tp  += __popcll(pw & dil3s(G, r, c));
        fnh += __popcll(gw & dil3s(P, r, c));
    }
    #pragma unroll
    for (int o = 32; o > 0; o >>= 1) {
        cp  += __shfl_down(cp, o);
        cg  += __shfl_down(cg, o);
        tp  += __shfl_down(tp, o);
        fnh += __shfl_down(fnh, o);
    }
    if ((tid & 63) == 0) {
        atomicAdd(&acc[0], cp);
        atomicAdd(&acc[1], cg);
        atomicAdd(&acc[2], tp);
        atomicAdd(&acc[3], fnh);
    }
    __syncthreads();
    if (tid < 4) atomicAdd(&cnt[b * 4 + tid], acc[tid]);
}

__global__ void ccq_reduce(const int* __restrict__ cnt, float* __restrict__ out) {
    int k = threadIdx.x;
    if (k < 3) {
        float s = 0.0f;
        for (int b = 0; b < NB; ++b) {
            float TP = (float)cnt[b * 4 + 2];
            float FP = (float)(cnt[b * 4 + 0] - cnt[b * 4 + 2]);
            float FN = (float)(cnt[b * 4 + 1] - cnt[b * 4 + 3]);
            float v = (k == 0) ? TP / (TP + FP + 1e-12f)
                    : (k == 1) ? TP / (TP + FN + 1e-12f)
                               : TP / (TP + FP + FN + 1e-12f);
            s += v;
        }
        out[k] = s * (1.0f / NB);
    }
}

extern "C" void kernel_launch(void* const* d_in, const int* in_sizes, int n_in,
                              void* d_out, int out_size, void* d_ws, size_t ws_size,
                              hipStream_t stream) {
    (void)in_sizes; (void)n_in; (void)out_size; (void)ws_size;
    const float* y_pred = (const float*)d_in[0];
    const float* y_true = (const float*)d_in[1];
    float* out = (float*)d_out;

    u64* skel = (u64*)d_ws;                               // 32 * 4096 * 8 = 1 MB
    int* cnt = (int*)((char*)d_ws + (size_t)2 * NB * NWORDS * sizeof(u64)); // 64 ints

    hipLaunchKernelGGL(skel_kernel, dim3(2 * NB), dim3(NTHREADS), 0, stream,
                       y_pred, y_true, skel, cnt);
    hipLaunchKernelGGL(count_kernel, dim3(NB * STRIPS), dim3(256), 0, stream,
                       skel, cnt);
    hipLaunchKernelGGL(ccq_reduce, dim3(1), dim3(64), 0, stream, cnt, out);
}